// Round 1
// baseline (409.025 us; speedup 1.0000x reference)
//
#include <hip/hip_runtime.h>
#include <hip/hip_bf16.h>

// Elementwise: y = x*2 + 5 - 3/(1+x), fp32 in/out, 8192*8192 elements.
// Memory-bound: 512 MB total traffic -> ~81 us floor at 6.3 TB/s achievable.
// float4 vectorized (16 B/lane), one float4 per thread.

__global__ __launch_bounds__(256) void ew_kernel(const float4* __restrict__ in,
                                                 float4* __restrict__ out,
                                                 int n4) {
    int i = blockIdx.x * blockDim.x + threadIdx.x;
    if (i < n4) {
        float4 x = in[i];
        float4 y;
        y.x = x.x * 2.0f + 5.0f - 3.0f / (1.0f + x.x);
        y.y = x.y * 2.0f + 5.0f - 3.0f / (1.0f + x.y);
        y.z = x.z * 2.0f + 5.0f - 3.0f / (1.0f + x.z);
        y.w = x.w * 2.0f + 5.0f - 3.0f / (1.0f + x.w);
        out[i] = y;
    }
}

// Scalar tail kernel not needed: 8192*8192 = 67108864 is divisible by 4,
// but keep a guard for generality via the scalar fallback below.
__global__ void ew_tail(const float* __restrict__ in, float* __restrict__ out,
                        int start, int n) {
    int i = start + blockIdx.x * blockDim.x + threadIdx.x;
    if (i < n) {
        float x = in[i];
        out[i] = x * 2.0f + 5.0f - 3.0f / (1.0f + x);
    }
}

extern "C" void kernel_launch(void* const* d_in, const int* in_sizes, int n_in,
                              void* d_out, int out_size, void* d_ws, size_t ws_size,
                              hipStream_t stream) {
    const float* in = (const float*)d_in[0];
    float* out = (float*)d_out;
    int n = in_sizes[0];
    int n4 = n / 4;

    if (n4 > 0) {
        int block = 256;
        int grid = (n4 + block - 1) / block;
        ew_kernel<<<grid, block, 0, stream>>>((const float4*)in, (float4*)out, n4);
    }
    int tail_start = n4 * 4;
    int tail = n - tail_start;
    if (tail > 0) {
        ew_tail<<<1, 64, 0, stream>>>(in, out, tail_start, tail);
    }
}